// Round 12
// baseline (821.097 us; speedup 1.0000x reference)
//
#include <hip/hip_runtime.h>
#include <hip/hip_cooperative_groups.h>
namespace cg = cooperative_groups;

typedef _Float16 f16;
typedef f16 f16x2 __attribute__((ext_vector_type(2)));
typedef f16 f16x8 __attribute__((ext_vector_type(8)));
typedef float f32x4 __attribute__((ext_vector_type(4)));

#define BSH 7                  // 128 nodes per bucket
#define BN 128
#define CHUNK 4096             // edges per count/place block
#define LCAP 4096              // LDS edge cap per bucket (mean ~2046, +45 sigma)
#define NBMAX 512
#define PMAX 512               // padded partial count (nb2 <= 512)

struct Params {
    const float* x;
    const int* src;
    const int* dst;
    const float* W1;
    const float* b1;
    const float* W2;
    const float* b2;
    f16* h;
    int* histG;
    int* bsum;
    int* sorted;
    int* rowstart;
    float* dinv;
    int* csr_src;
    f16* r1;
    f16* h2;
    float* out;
    int N, E, NB, nblk, L, nb2, ntile;
};

// ---- exclusive-scan bsum[nb2] into excl[PMAX] using work[PMAX] (256 threads) ----
__device__ __forceinline__ void scan_partials(const int* __restrict__ bsum, int nb2, int* excl,
                                              int* work) {
    const int t = threadIdx.x;
    for (int i = t; i < PMAX; i += 256) work[i] = (i < nb2) ? bsum[i] : 0;
    __syncthreads();
    for (int o = 1; o < PMAX; o <<= 1) {
        for (int i = t; i < PMAX; i += 256) excl[i] = work[i] + ((i >= o) ? work[i - o] : 0);
        __syncthreads();
        for (int i = t; i < PMAX; i += 256) work[i] = excl[i];
        __syncthreads();
    }
    for (int i = t; i < PMAX; i += 256) excl[i] = (i == 0) ? 0 : work[i - 1];
    __syncthreads();
}

// ==================== cooperative mega-kernel (all 7 phases) ====================
// LDS capped at 26624 B -> 6 blocks/CU; launch_bounds(256,6) caps VGPR <= 85.
__global__ __launch_bounds__(256, 6) void mega(Params p) {
    cg::grid_group grid = cg::this_grid();
    __shared__ __align__(16) char smem[26624];
    const int b = blockIdx.x, t = threadIdx.x, G = gridDim.x;
    const int w = t >> 6, lane = t & 63, m15 = lane & 15, quad = lane >> 4;

    // ---------------- P1: bucket-hist chunks ++ MFMA gemm1 tiles ----------------
    for (int job = b; job < p.nblk + p.ntile; job += G) {
        __syncthreads();  // smem reuse across jobs
        if (job < p.nblk) {
            int* hist = (int*)smem;
            for (int i = t; i < p.NB; i += 256) hist[i] = 0;
            __syncthreads();
            int lo = job * CHUNK, hi = min(lo + CHUNK, p.E);
            for (int i = lo + t; i < hi; i += 256) atomicAdd(&hist[p.dst[i] >> BSH], 1);
            __syncthreads();
            for (int i = t; i < p.NB; i += 256) p.histG[(size_t)i * p.nblk + job] = hist[i];
        } else {
            f16* aT = (f16*)smem;             // [64][136]
            f16* bTq = (f16*)(smem + 17408);  // [128][36] k-quarter
            const int row0 = (job - p.nblk) * 64;
            {  // stage A fp32->f16, full k
                int r = t >> 2, s = (t & 3) * 32;
                bool ok = (row0 + r) < p.N;
                const float* xp = p.x + (size_t)(row0 + r) * 128 + s;
                f16* dp = &aT[r * 136 + s];
#pragma unroll
                for (int c = 0; c < 4; ++c) {
                    f16x8 hv;
                    if (ok) {
                        float4 f0 = *(const float4*)(xp + c * 8);
                        float4 f1 = *(const float4*)(xp + c * 8 + 4);
                        hv[0] = (f16)f0.x; hv[1] = (f16)f0.y; hv[2] = (f16)f0.z; hv[3] = (f16)f0.w;
                        hv[4] = (f16)f1.x; hv[5] = (f16)f1.y; hv[6] = (f16)f1.z; hv[7] = (f16)f1.w;
                    } else {
#pragma unroll
                        for (int j = 0; j < 8; ++j) hv[j] = (f16)0.f;
                    }
                    *(f16x8*)(dp + c * 8) = hv;
                }
            }
            f32x4 acc[8];
#pragma unroll
            for (int c = 0; c < 8; ++c) acc[c] = (f32x4){0.f, 0.f, 0.f, 0.f};
#pragma unroll
            for (int kq = 0; kq < 4; ++kq) {
                __syncthreads();
                for (int idx = t; idx < 128 * 32; idx += 256) {  // stage W1^T k-quarter
                    int k = idx >> 7, n = idx & 127;
                    bTq[n * 36 + k] = (f16)p.W1[(size_t)(kq * 32 + k) * 128 + n];
                }
                __syncthreads();
                f16x8 a = *(const f16x8*)(&aT[(w * 16 + m15) * 136 + kq * 32 + quad * 8]);
#pragma unroll
                for (int c = 0; c < 8; ++c) {
                    f16x8 bb = *(const f16x8*)(&bTq[(c * 16 + m15) * 36 + quad * 8]);
                    acc[c] = __builtin_amdgcn_mfma_f32_16x16x32_f16(a, bb, acc[c], 0, 0, 0);
                }
            }
#pragma unroll
            for (int c = 0; c < 8; ++c)
#pragma unroll
                for (int r = 0; r < 4; ++r) {
                    int row = row0 + w * 16 + quad * 4 + r;
                    if (row < p.N) p.h[(size_t)row * 128 + c * 16 + m15] = (f16)acc[c][r];
                }
        }
    }
    grid.sync();

    // ---------------- P2: chunk-local scan of histG ----------------
    {
        int* tmp = (int*)smem;
        for (int job = b; job < p.nb2; job += G) {
            __syncthreads();
            int i = job * 256 + t;
            int v = (i < p.L) ? p.histG[i] : 0;
            tmp[t] = v;
            __syncthreads();
            for (int o = 1; o < 256; o <<= 1) {
                int t2 = (t >= o) ? tmp[t - o] : 0;
                __syncthreads();
                tmp[t] += t2;
                __syncthreads();
            }
            if (i < p.L) p.histG[i] = tmp[t] - v;
            if (t == 255) p.bsum[job] = tmp[255];
        }
    }
    grid.sync();

    // ---------------- P3: place edges bucket-contiguously ----------------
    {
        int* excl = (int*)smem;
        int* work = (int*)(smem + 2048);
        int* ofs = (int*)(smem + 4096);
        scan_partials(p.bsum, p.nb2, excl, work);
        for (int job = b; job < p.nblk; job += G) {
            __syncthreads();
            for (int i = t; i < p.NB; i += 256) {
                int idx = i * p.nblk + job;
                ofs[i] = p.histG[idx] + excl[idx >> 8];
            }
            __syncthreads();
            int lo = job * CHUNK, hi = min(lo + CHUNK, p.E);
            for (int i = lo + t; i < hi; i += 256) {
                int d = p.dst[i];
                int pos = atomicAdd(&ofs[d >> BSH], 1);
                p.sorted[pos] = (p.src[i] << BSH) | (d & (BN - 1));
            }
        }
    }
    grid.sync();

    // ---------------- P4: per-bucket node sort -> rowstart, dinv, csr_src ----------------
    {
        int* ent = (int*)smem;             // 4096 ints
        int* hist = (int*)(smem + 16384);  // 128
        int* lofs = (int*)(smem + 16896);  // 128
        int* excl = (int*)(smem + 17408);  // 512
        int* work = (int*)(smem + 19456);  // 512
        scan_partials(p.bsum, p.nb2, excl, work);
        if (b == 0 && t == 0) p.rowstart[p.N] = p.E;
        for (int job = b; job < p.NB; job += G) {
            __syncthreads();
            const int i0 = job * p.nblk;
            const int base = p.histG[i0] + excl[i0 >> 8];
            const int endb =
                (job == p.NB - 1) ? p.E : (p.histG[i0 + p.nblk] + excl[(i0 + p.nblk) >> 8]);
            int total = min(endb - base, LCAP);
            for (int i = t; i < total; i += 256) ent[i] = p.sorted[base + i];
            if (t < BN) hist[t] = 0;
            __syncthreads();
            for (int i = t; i < total; i += 256) atomicAdd(&hist[ent[i] & (BN - 1)], 1);
            __syncthreads();
            if (t < BN) lofs[t] = hist[t];
            __syncthreads();
            for (int o = 1; o < BN; o <<= 1) {
                int v = (t < BN && t >= o) ? lofs[t - o] : 0;
                __syncthreads();
                if (t < BN) lofs[t] += v;
                __syncthreads();
            }
            if (t < BN) {
                int ex = lofs[t] - hist[t];
                int node = (job << BSH) + t;
                if (node < p.N) {
                    p.rowstart[node] = base + ex;
                    p.dinv[node] = rsqrtf((float)hist[t] + 1.0f);
                }
                lofs[t] = ex;
            }
            __syncthreads();
            for (int i = t; i < total; i += 256) {
                int e = ent[i];
                int pos = atomicAdd(&lofs[e & (BN - 1)], 1);
                p.csr_src[base + pos] = e >> BSH;
            }
        }
    }
    grid.sync();

    // ---------------- P5: gather1 + b1 + relu -> r1 (1 wave/node) ----------------
    {
        const f16x2* hv = (const f16x2*)p.h;
        const int nwave = G * 4;
        for (int node = b * 4 + w; node < p.N; node += nwave) {
            int beg = p.rowstart[node], end = p.rowstart[node + 1];
            float dn = p.dinv[node];
            f16x2 sv = hv[(size_t)node * 64 + lane];
            float ax = dn * (float)sv[0], ay = dn * (float)sv[1];
            int i = beg;
            for (; i + 4 <= end; i += 4) {
                int s0 = p.csr_src[i], s1 = p.csr_src[i + 1];
                int s2 = p.csr_src[i + 2], s3 = p.csr_src[i + 3];
                float w0 = p.dinv[s0], w1 = p.dinv[s1], w2 = p.dinv[s2], w3 = p.dinv[s3];
                f16x2 v0 = hv[(size_t)s0 * 64 + lane];
                f16x2 v1 = hv[(size_t)s1 * 64 + lane];
                f16x2 v2 = hv[(size_t)s2 * 64 + lane];
                f16x2 v3 = hv[(size_t)s3 * 64 + lane];
                ax = fmaf(w0, (float)v0[0], ax); ay = fmaf(w0, (float)v0[1], ay);
                ax = fmaf(w1, (float)v1[0], ax); ay = fmaf(w1, (float)v1[1], ay);
                ax = fmaf(w2, (float)v2[0], ax); ay = fmaf(w2, (float)v2[1], ay);
                ax = fmaf(w3, (float)v3[0], ax); ay = fmaf(w3, (float)v3[1], ay);
            }
            for (; i < end; ++i) {
                int s = p.csr_src[i];
                float ws = p.dinv[s];
                f16x2 v = hv[(size_t)s * 64 + lane];
                ax = fmaf(ws, (float)v[0], ax);
                ay = fmaf(ws, (float)v[1], ay);
            }
            float2 bb = ((const float2*)p.b1)[lane];
            float ox = fmaxf(fmaf(dn, ax, bb.x), 0.f);
            float oy = fmaxf(fmaf(dn, ay, bb.y), 0.f);
            ((f16x2*)p.r1)[(size_t)node * 64 + lane] = (f16x2){(f16)ox, (f16)oy};
        }
    }
    grid.sync();

    // ---------------- P6: MFMA gemm2: h2 = r1 @ W2 ----------------
    {
        f16* aT = (f16*)smem;             // [64][136]
        f16* bTq = (f16*)(smem + 17408);  // [64][36] k-quarter
        for (int job = b; job < p.ntile; job += G) {
            __syncthreads();
            const int row0 = job * 64;
            {
                int r = t >> 2, s = (t & 3) * 32;
                bool ok = (row0 + r) < p.N;
                const f16* rp = p.r1 + (size_t)(row0 + r) * 128 + s;
                f16* dp = &aT[r * 136 + s];
#pragma unroll
                for (int c = 0; c < 4; ++c) {
                    f16x8 hv;
                    if (ok) hv = *(const f16x8*)(rp + c * 8);
                    else {
#pragma unroll
                        for (int j = 0; j < 8; ++j) hv[j] = (f16)0.f;
                    }
                    *(f16x8*)(dp + c * 8) = hv;
                }
            }
            f32x4 acc[4];
#pragma unroll
            for (int c = 0; c < 4; ++c) acc[c] = (f32x4){0.f, 0.f, 0.f, 0.f};
#pragma unroll
            for (int kq = 0; kq < 4; ++kq) {
                __syncthreads();
                for (int idx = t; idx < 64 * 32; idx += 256) {  // stage W2^T k-quarter
                    int k = idx >> 6, n = idx & 63;
                    bTq[n * 36 + k] = (f16)p.W2[(size_t)(kq * 32 + k) * 64 + n];
                }
                __syncthreads();
                f16x8 a = *(const f16x8*)(&aT[(w * 16 + m15) * 136 + kq * 32 + quad * 8]);
#pragma unroll
                for (int c = 0; c < 4; ++c) {
                    f16x8 bb = *(const f16x8*)(&bTq[(c * 16 + m15) * 36 + quad * 8]);
                    acc[c] = __builtin_amdgcn_mfma_f32_16x16x32_f16(a, bb, acc[c], 0, 0, 0);
                }
            }
#pragma unroll
            for (int c = 0; c < 4; ++c)
#pragma unroll
                for (int r = 0; r < 4; ++r) {
                    int row = row0 + w * 16 + quad * 4 + r;
                    if (row < p.N) p.h2[(size_t)row * 64 + c * 16 + m15] = (f16)acc[c][r];
                }
        }
    }
    grid.sync();

    // ---------------- P7: gather2 + b2 -> out (2 nodes/wave) ----------------
    {
        const f16x2* h2v = (const f16x2*)p.h2;
        const int sub = lane >> 5, l32 = lane & 31;
        const int npair = (p.N + 1) >> 1;
        const int nwave = G * 4;
        for (int pr = b * 4 + w; pr < npair; pr += nwave) {
            int node = pr * 2 + sub;
            if (node < p.N) {
                int beg = p.rowstart[node], end = p.rowstart[node + 1];
                float dn = p.dinv[node];
                f16x2 sv = h2v[(size_t)node * 32 + l32];
                float ax = dn * (float)sv[0], ay = dn * (float)sv[1];
                int i = beg;
                for (; i + 4 <= end; i += 4) {
                    int s0 = p.csr_src[i], s1 = p.csr_src[i + 1];
                    int s2 = p.csr_src[i + 2], s3 = p.csr_src[i + 3];
                    float w0 = p.dinv[s0], w1 = p.dinv[s1], w2 = p.dinv[s2], w3 = p.dinv[s3];
                    f16x2 v0 = h2v[(size_t)s0 * 32 + l32];
                    f16x2 v1 = h2v[(size_t)s1 * 32 + l32];
                    f16x2 v2 = h2v[(size_t)s2 * 32 + l32];
                    f16x2 v3 = h2v[(size_t)s3 * 32 + l32];
                    ax = fmaf(w0, (float)v0[0], ax); ay = fmaf(w0, (float)v0[1], ay);
                    ax = fmaf(w1, (float)v1[0], ax); ay = fmaf(w1, (float)v1[1], ay);
                    ax = fmaf(w2, (float)v2[0], ax); ay = fmaf(w2, (float)v2[1], ay);
                    ax = fmaf(w3, (float)v3[0], ax); ay = fmaf(w3, (float)v3[1], ay);
                }
                for (; i < end; ++i) {
                    int s = p.csr_src[i];
                    float ws = p.dinv[s];
                    f16x2 v = h2v[(size_t)s * 32 + l32];
                    ax = fmaf(ws, (float)v[0], ax);
                    ay = fmaf(ws, (float)v[1], ay);
                }
                float2 bb = ((const float2*)p.b2)[l32];
                float2 o;
                o.x = fmaf(dn, ax, bb.x);
                o.y = fmaf(dn, ay, bb.y);
                ((float2*)p.out)[(size_t)node * 32 + l32] = o;
            }
        }
    }
}

// ==================== fallback kernels (R11, proven 194 us) ====================
__global__ __launch_bounds__(256) void k1(const float* __restrict__ x,
                                          const float* __restrict__ W1,
                                          const int* __restrict__ dst, f16* __restrict__ h,
                                          int* __restrict__ histG, int N, int E, int NB,
                                          int nblk) {
    __shared__ int hist[NBMAX];
    __shared__ f16 aT[64 * 136];
    __shared__ f16 bT[128 * 136];
    const int t = threadIdx.x;
    if ((int)blockIdx.x < nblk) {
        const int blk = blockIdx.x;
        for (int i = t; i < NB; i += 256) hist[i] = 0;
        __syncthreads();
        int lo = blk * CHUNK, hi = min(lo + CHUNK, E);
        for (int i = lo + t; i < hi; i += 256) atomicAdd(&hist[dst[i] >> BSH], 1);
        __syncthreads();
        for (int i = t; i < NB; i += 256) histG[(size_t)i * nblk + blk] = hist[i];
        return;
    }
    const int gb = blockIdx.x - nblk;
    const int row0 = gb * 64;
    {
        int r = t >> 2, s = (t & 3) * 32;
        bool ok = (row0 + r) < N;
        const float* xp = x + (size_t)(row0 + r) * 128 + s;
        f16* dp = &aT[r * 136 + s];
#pragma unroll
        for (int c = 0; c < 4; ++c) {
            f16x8 hv;
            if (ok) {
                float4 f0 = *(const float4*)(xp + c * 8);
                float4 f1 = *(const float4*)(xp + c * 8 + 4);
                hv[0] = (f16)f0.x; hv[1] = (f16)f0.y; hv[2] = (f16)f0.z; hv[3] = (f16)f0.w;
                hv[4] = (f16)f1.x; hv[5] = (f16)f1.y; hv[6] = (f16)f1.z; hv[7] = (f16)f1.w;
            } else {
#pragma unroll
                for (int j = 0; j < 8; ++j) hv[j] = (f16)0.f;
            }
            *(f16x8*)(dp + c * 8) = hv;
        }
    }
    for (int idx = t; idx < 128 * 128; idx += 256) {
        int k = idx >> 7, n = idx & 127;
        bT[n * 136 + k] = (f16)W1[idx];
    }
    __syncthreads();
    const int w = t >> 6, lane = t & 63, m15 = lane & 15, quad = lane >> 4;
    f32x4 acc[8];
#pragma unroll
    for (int c = 0; c < 8; ++c) acc[c] = (f32x4){0.f, 0.f, 0.f, 0.f};
    const f16* ar = &aT[(w * 16 + m15) * 136 + quad * 8];
#pragma unroll
    for (int k0 = 0; k0 < 128; k0 += 32) {
        f16x8 a = *(const f16x8*)(ar + k0);
#pragma unroll
        for (int c = 0; c < 8; ++c) {
            f16x8 b = *(const f16x8*)(&bT[(c * 16 + m15) * 136 + k0 + quad * 8]);
            acc[c] = __builtin_amdgcn_mfma_f32_16x16x32_f16(a, b, acc[c], 0, 0, 0);
        }
    }
#pragma unroll
    for (int c = 0; c < 8; ++c)
#pragma unroll
        for (int r = 0; r < 4; ++r) {
            int row = row0 + w * 16 + quad * 4 + r;
            if (row < N) h[(size_t)row * 128 + c * 16 + m15] = (f16)acc[c][r];
        }
}

__global__ __launch_bounds__(256) void scanAk(int* __restrict__ a, int* __restrict__ bsum,
                                              int L) {
    __shared__ int tmp[256];
    int tid = threadIdx.x;
    int i = blockIdx.x * 256 + tid;
    int v = (i < L) ? a[i] : 0;
    tmp[tid] = v;
    __syncthreads();
    for (int o = 1; o < 256; o <<= 1) {
        int t2 = (tid >= o) ? tmp[tid - o] : 0;
        __syncthreads();
        tmp[tid] += t2;
        __syncthreads();
    }
    if (i < L) a[i] = tmp[tid] - v;
    if (tid == 255) bsum[blockIdx.x] = tmp[255];
}

__global__ __launch_bounds__(256) void placek(const int* __restrict__ src,
                                              const int* __restrict__ dst,
                                              const int* __restrict__ histG,
                                              const int* __restrict__ bsum, int nb2,
                                              int* __restrict__ sorted, int E, int NB,
                                              int nblk) {
    __shared__ int excl[PMAX];
    __shared__ int work[PMAX];
    __shared__ int ofs[NBMAX];
    const int t = threadIdx.x, blk = blockIdx.x;
    scan_partials(bsum, nb2, excl, work);
    for (int i = t; i < NB; i += 256) {
        int idx = i * nblk + blk;
        ofs[i] = histG[idx] + excl[idx >> 8];
    }
    __syncthreads();
    int lo = blk * CHUNK, hi = min(lo + CHUNK, E);
    for (int i = lo + t; i < hi; i += 256) {
        int d = dst[i];
        int pos = atomicAdd(&ofs[d >> BSH], 1);
        sorted[pos] = (src[i] << BSH) | (d & (BN - 1));
    }
}

__global__ __launch_bounds__(256) void buildk(const int* __restrict__ histG,
                                              const int* __restrict__ bsum, int nb2,
                                              const int* __restrict__ sorted,
                                              int* __restrict__ rowstart,
                                              float* __restrict__ dinv,
                                              int* __restrict__ csr_src, int N, int E, int NB,
                                              int nblk) {
    __shared__ int ent[LCAP];
    __shared__ int hist[BN];
    __shared__ int lofs[BN];
    __shared__ int excl[PMAX];
    __shared__ int work[PMAX];
    const int b = blockIdx.x, t = threadIdx.x;
    scan_partials(bsum, nb2, excl, work);
    const int i0 = b * nblk;
    const int base = histG[i0] + excl[i0 >> 8];
    const int endb = (b == NB - 1) ? E : (histG[i0 + nblk] + excl[(i0 + nblk) >> 8]);
    int total = min(endb - base, LCAP);
    if (b == 0 && t == 0) rowstart[N] = E;
    for (int i = t; i < total; i += 256) ent[i] = sorted[base + i];
    if (t < BN) hist[t] = 0;
    __syncthreads();
    for (int i = t; i < total; i += 256) atomicAdd(&hist[ent[i] & (BN - 1)], 1);
    __syncthreads();
    if (t < BN) lofs[t] = hist[t];
    __syncthreads();
    for (int o = 1; o < BN; o <<= 1) {
        int v = (t < BN && t >= o) ? lofs[t - o] : 0;
        __syncthreads();
        if (t < BN) lofs[t] += v;
        __syncthreads();
    }
    if (t < BN) {
        int ex = lofs[t] - hist[t];
        int node = (b << BSH) + t;
        if (node < N) {
            rowstart[node] = base + ex;
            dinv[node] = rsqrtf((float)hist[t] + 1.0f);
        }
        lofs[t] = ex;
    }
    __syncthreads();
    for (int i = t; i < total; i += 256) {
        int e = ent[i];
        int pos = atomicAdd(&lofs[e & (BN - 1)], 1);
        csr_src[base + pos] = e >> BSH;
    }
}

__global__ __launch_bounds__(256) void gather1k(const int* __restrict__ rowstart,
                                                const int* __restrict__ csr_src,
                                                const float* __restrict__ dinv,
                                                const f16* __restrict__ h,
                                                const float* __restrict__ b1,
                                                f16* __restrict__ r1, int N) {
    int node = (blockIdx.x * 256 + threadIdx.x) >> 6;
    int lane = threadIdx.x & 63;
    if (node >= N) return;
    int beg = rowstart[node], end = rowstart[node + 1];
    float dn = dinv[node];
    const f16x2* hv = (const f16x2*)h;
    f16x2 sv = hv[(size_t)node * 64 + lane];
    float ax = dn * (float)sv[0], ay = dn * (float)sv[1];
    int i = beg;
    for (; i + 4 <= end; i += 4) {
        int s0 = csr_src[i], s1 = csr_src[i + 1], s2 = csr_src[i + 2], s3 = csr_src[i + 3];
        float w0 = dinv[s0], w1 = dinv[s1], w2 = dinv[s2], w3 = dinv[s3];
        f16x2 v0 = hv[(size_t)s0 * 64 + lane];
        f16x2 v1 = hv[(size_t)s1 * 64 + lane];
        f16x2 v2 = hv[(size_t)s2 * 64 + lane];
        f16x2 v3 = hv[(size_t)s3 * 64 + lane];
        ax = fmaf(w0, (float)v0[0], ax); ay = fmaf(w0, (float)v0[1], ay);
        ax = fmaf(w1, (float)v1[0], ax); ay = fmaf(w1, (float)v1[1], ay);
        ax = fmaf(w2, (float)v2[0], ax); ay = fmaf(w2, (float)v2[1], ay);
        ax = fmaf(w3, (float)v3[0], ax); ay = fmaf(w3, (float)v3[1], ay);
    }
    for (; i < end; ++i) {
        int s = csr_src[i];
        float w = dinv[s];
        f16x2 v = hv[(size_t)s * 64 + lane];
        ax = fmaf(w, (float)v[0], ax);
        ay = fmaf(w, (float)v[1], ay);
    }
    float2 bb = ((const float2*)b1)[lane];
    float ox = fmaxf(fmaf(dn, ax, bb.x), 0.f);
    float oy = fmaxf(fmaf(dn, ay, bb.y), 0.f);
    ((f16x2*)r1)[(size_t)node * 64 + lane] = (f16x2){(f16)ox, (f16)oy};
}

__global__ __launch_bounds__(256) void gemm2k(const f16* __restrict__ r1,
                                              const float* __restrict__ W2,
                                              f16* __restrict__ h2, int N) {
    __shared__ f16 aT[64 * 136];
    __shared__ f16 bT[64 * 136];
    const int t = threadIdx.x;
    const int row0 = blockIdx.x * 64;
    {
        int r = t >> 2, s = (t & 3) * 32;
        bool ok = (row0 + r) < N;
        const f16* rp = r1 + (size_t)(row0 + r) * 128 + s;
        f16* dp = &aT[r * 136 + s];
#pragma unroll
        for (int c = 0; c < 4; ++c) {
            f16x8 hv;
            if (ok) hv = *(const f16x8*)(rp + c * 8);
            else {
#pragma unroll
                for (int j = 0; j < 8; ++j) hv[j] = (f16)0.f;
            }
            *(f16x8*)(dp + c * 8) = hv;
        }
    }
    for (int idx = t; idx < 128 * 64; idx += 256) {
        int k = idx >> 6, n = idx & 63;
        bT[n * 136 + k] = (f16)W2[idx];
    }
    __syncthreads();
    const int w = t >> 6, lane = t & 63, m15 = lane & 15, quad = lane >> 4;
    f32x4 acc[4];
#pragma unroll
    for (int c = 0; c < 4; ++c) acc[c] = (f32x4){0.f, 0.f, 0.f, 0.f};
    const f16* ar = &aT[(w * 16 + m15) * 136 + quad * 8];
#pragma unroll
    for (int k0 = 0; k0 < 128; k0 += 32) {
        f16x8 a = *(const f16x8*)(ar + k0);
#pragma unroll
        for (int c = 0; c < 4; ++c) {
            f16x8 b = *(const f16x8*)(&bT[(c * 16 + m15) * 136 + k0 + quad * 8]);
            acc[c] = __builtin_amdgcn_mfma_f32_16x16x32_f16(a, b, acc[c], 0, 0, 0);
        }
    }
#pragma unroll
    for (int c = 0; c < 4; ++c)
#pragma unroll
        for (int r = 0; r < 4; ++r) {
            int row = row0 + w * 16 + quad * 4 + r;
            if (row < N) h2[(size_t)row * 64 + c * 16 + m15] = (f16)acc[c][r];
        }
}

__global__ __launch_bounds__(256) void gather2k(const int* __restrict__ rowstart,
                                                const int* __restrict__ csr_src,
                                                const float* __restrict__ dinv,
                                                const f16* __restrict__ h2,
                                                const float* __restrict__ b2,
                                                float* __restrict__ out, int N) {
    int pair = (blockIdx.x * 256 + threadIdx.x) >> 6;
    int lane = threadIdx.x & 63;
    int sub = lane >> 5, l32 = lane & 31;
    int node = pair * 2 + sub;
    if (node >= N) return;
    int beg = rowstart[node], end = rowstart[node + 1];
    float dn = dinv[node];
    const f16x2* h2v = (const f16x2*)h2;
    f16x2 sv = h2v[(size_t)node * 32 + l32];
    float ax = dn * (float)sv[0], ay = dn * (float)sv[1];
    int i = beg;
    for (; i + 4 <= end; i += 4) {
        int s0 = csr_src[i], s1 = csr_src[i + 1], s2 = csr_src[i + 2], s3 = csr_src[i + 3];
        float w0 = dinv[s0], w1 = dinv[s1], w2 = dinv[s2], w3 = dinv[s3];
        f16x2 v0 = h2v[(size_t)s0 * 32 + l32];
        f16x2 v1 = h2v[(size_t)s1 * 32 + l32];
        f16x2 v2 = h2v[(size_t)s2 * 32 + l32];
        f16x2 v3 = h2v[(size_t)s3 * 32 + l32];
        ax = fmaf(w0, (float)v0[0], ax); ay = fmaf(w0, (float)v0[1], ay);
        ax = fmaf(w1, (float)v1[0], ax); ay = fmaf(w1, (float)v1[1], ay);
        ax = fmaf(w2, (float)v2[0], ax); ay = fmaf(w2, (float)v2[1], ay);
        ax = fmaf(w3, (float)v3[0], ax); ay = fmaf(w3, (float)v3[1], ay);
    }
    for (; i < end; ++i) {
        int s = csr_src[i];
        float w = dinv[s];
        f16x2 v = h2v[(size_t)s * 32 + l32];
        ax = fmaf(w, (float)v[0], ax);
        ay = fmaf(w, (float)v[1], ay);
    }
    float2 bb = ((const float2*)b2)[l32];
    float2 o;
    o.x = fmaf(dn, ax, bb.x);
    o.y = fmaf(dn, ay, bb.y);
    ((float2*)out)[(size_t)node * 32 + l32] = o;
}

extern "C" void kernel_launch(void* const* d_in, const int* in_sizes, int n_in,
                              void* d_out, int out_size, void* d_ws, size_t ws_size,
                              hipStream_t stream) {
    const int N = in_sizes[0] / 128;  // 50000
    const int E = in_sizes[1] / 2;    // 800000

    Params p;
    p.x = (const float*)d_in[0];
    p.src = (const int*)d_in[1];
    p.dst = (const int*)d_in[1] + E;
    p.W1 = (const float*)d_in[2];
    p.b1 = (const float*)d_in[3];
    p.W2 = (const float*)d_in[4];
    p.b2 = (const float*)d_in[5];
    p.N = N;
    p.E = E;
    p.NB = (N + BN - 1) >> BSH;        // 391
    p.nblk = (E + CHUNK - 1) / CHUNK;  // 196
    p.L = p.NB * p.nblk;               // 76,636
    p.nb2 = (p.L + 255) / 256;         // 300
    p.ntile = (N + 63) / 64;           // 782

    char* q = (char*)d_ws;
    auto bump = [&](size_t bytes) {
        char* r = q;
        q += (bytes + 255) & ~(size_t)255;
        return r;
    };
    p.histG    = (int*)bump((size_t)p.L * 4);
    p.bsum     = (int*)bump((size_t)p.nb2 * 4);
    p.sorted   = (int*)bump((size_t)E * 4);
    p.rowstart = (int*)bump((size_t)(N + 1) * 4);
    p.dinv     = (float*)bump((size_t)N * 4);
    p.csr_src  = (int*)bump((size_t)E * 4);
    p.h        = (f16*)bump((size_t)N * 128 * 2);
    p.r1       = (f16*)bump((size_t)N * 128 * 2);
    p.h2       = (f16*)bump((size_t)N * 64 * 2);
    p.out      = (float*)d_out;

    // ---- try cooperative single-dispatch path (guarded) ----
    int coopAttr = 0, dev = 0, maxB = 0, cus = 256;
    hipGetDevice(&dev);
    hipDeviceGetAttribute(&coopAttr, hipDeviceAttributeCooperativeLaunch, dev);
    hipError_t qe =
        hipOccupancyMaxActiveBlocksPerMultiprocessor(&maxB, (const void*)mega, 256, 0);
    hipDeviceProp_t prop;
    if (hipGetDeviceProperties(&prop, dev) == hipSuccess) cus = prop.multiProcessorCount;
    if (coopAttr && qe == hipSuccess && maxB >= 1) {
        int GRIDn = maxB * cus;
        if (GRIDn > 2048) GRIDn = 2048;
        void* kargs[] = {&p};
        if (hipLaunchCooperativeKernel((const void*)mega, dim3(GRIDn), dim3(256), kargs, 0,
                                       stream) == hipSuccess)
            return;
    }

    // ---- fallback: proven 7-kernel path (R11) ----
    k1<<<p.nblk + p.ntile, 256, 0, stream>>>(p.x, p.W1, p.dst, p.h, p.histG, N, E, p.NB, p.nblk);
    scanAk<<<p.nb2, 256, 0, stream>>>(p.histG, p.bsum, p.L);
    placek<<<p.nblk, 256, 0, stream>>>(p.src, p.dst, p.histG, p.bsum, p.nb2, p.sorted, E, p.NB,
                                       p.nblk);
    buildk<<<p.NB, 256, 0, stream>>>(p.histG, p.bsum, p.nb2, p.sorted, p.rowstart, p.dinv,
                                     p.csr_src, N, E, p.NB, p.nblk);
    gather1k<<<(N + 3) / 4, 256, 0, stream>>>(p.rowstart, p.csr_src, p.dinv, p.h, p.b1, p.r1, N);
    gemm2k<<<(N + 63) / 64, 256, 0, stream>>>(p.r1, p.W2, p.h2, N);
    gather2k<<<(N / 2 + 3) / 4, 256, 0, stream>>>(p.rowstart, p.csr_src, p.dinv, p.h2, p.b2,
                                                  p.out, N);
}

// Round 13
// 280.118 us; speedup vs baseline: 2.9313x; 2.9313x over previous
//
#include <hip/hip_runtime.h>

typedef _Float16 f16;
typedef f16 f16x2 __attribute__((ext_vector_type(2)));
typedef f16 f16x4 __attribute__((ext_vector_type(4)));
typedef f16 f16x8 __attribute__((ext_vector_type(8)));
typedef float f32x4 __attribute__((ext_vector_type(4)));

#define BSH 7                  // 128 nodes per bucket
#define BN 128
#define CHUNK 4096             // edges per count/place block
#define LCAP 4096              // LDS edge cap per bucket (mean ~2046, +45 sigma)
#define NBMAX 512
#define PMAX 512

// ============ K1: bucket-hist (blocks 0..nblk) || MFMA GEMM1 (remaining blocks) ============
// histG layout: [blk][bucket] (transposed vs old) -> hist write is fully coalesced.
__global__ __launch_bounds__(256) void k1(const float* __restrict__ x,
                                          const float* __restrict__ W1,
                                          const int* __restrict__ dst, f16* __restrict__ h,
                                          int* __restrict__ histG, int N, int E, int NB,
                                          int nblk) {
    __shared__ int hist[NBMAX];
    __shared__ f16 aT[64 * 136];   // x tile [row][k]
    __shared__ f16 bT[128 * 136];  // W1^T  [n][k]
    const int t = threadIdx.x;

    if ((int)blockIdx.x < nblk) {  // ---- count role ----
        const int blk = blockIdx.x;
        for (int i = t; i < NB; i += 256) hist[i] = 0;
        __syncthreads();
        int lo = blk * CHUNK, hi = min(lo + CHUNK, E);
        for (int i = lo + t; i < hi; i += 256) atomicAdd(&hist[dst[i] >> BSH], 1);
        __syncthreads();
        for (int i = t; i < NB; i += 256) histG[(size_t)blk * NB + i] = hist[i];
        return;
    }

    // ---- gemm role: h[64 x 128] = x_tile @ W1 ----
    const int gb = blockIdx.x - nblk;
    const int row0 = gb * 64;
    {  // stage A (fp32 -> fp16), k-contiguous
        int r = t >> 2, s = (t & 3) * 32;
        bool ok = (row0 + r) < N;
        const float* xp = x + (size_t)(row0 + r) * 128 + s;
        f16* dp = &aT[r * 136 + s];
#pragma unroll
        for (int c = 0; c < 4; ++c) {
            f16x8 hv;
            if (ok) {
                float4 f0 = *(const float4*)(xp + c * 8);
                float4 f1 = *(const float4*)(xp + c * 8 + 4);
                hv[0] = (f16)f0.x; hv[1] = (f16)f0.y; hv[2] = (f16)f0.z; hv[3] = (f16)f0.w;
                hv[4] = (f16)f1.x; hv[5] = (f16)f1.y; hv[6] = (f16)f1.z; hv[7] = (f16)f1.w;
            } else {
#pragma unroll
                for (int j = 0; j < 8; ++j) hv[j] = (f16)0.f;
            }
            *(f16x8*)(dp + c * 8) = hv;
        }
    }
    for (int idx = t; idx < 128 * 128; idx += 256) {  // stage W1^T
        int k = idx >> 7, n = idx & 127;
        bT[n * 136 + k] = (f16)W1[idx];
    }
    __syncthreads();

    const int w = t >> 6, lane = t & 63, m15 = lane & 15, quad = lane >> 4;
    f32x4 acc[8];
#pragma unroll
    for (int c = 0; c < 8; ++c) acc[c] = (f32x4){0.f, 0.f, 0.f, 0.f};
    const f16* ar = &aT[(w * 16 + m15) * 136 + quad * 8];
#pragma unroll
    for (int k0 = 0; k0 < 128; k0 += 32) {
        f16x8 a = *(const f16x8*)(ar + k0);
#pragma unroll
        for (int c = 0; c < 8; ++c) {
            f16x8 b = *(const f16x8*)(&bT[(c * 16 + m15) * 136 + k0 + quad * 8]);
            acc[c] = __builtin_amdgcn_mfma_f32_16x16x32_f16(a, b, acc[c], 0, 0, 0);
        }
    }
#pragma unroll
    for (int c = 0; c < 8; ++c)
#pragma unroll
        for (int r = 0; r < 4; ++r) {
            int row = row0 + w * 16 + quad * 4 + r;
            if (row < N) h[(size_t)row * 128 + c * 16 + m15] = (f16)acc[c][r];
        }
}

// ============ K2: place edges into bucket-contiguous sorted[] ============
// Each block sums histG columns itself (L2-resident, coalesced): tot[i] over all
// chunk-blocks, pre[i] over chunk-blocks < blk. Block 0 publishes bucketBase.
__global__ __launch_bounds__(256) void place(const int* __restrict__ src,
                                             const int* __restrict__ dst,
                                             const int* __restrict__ histG,
                                             int* __restrict__ bucketBase,
                                             int* __restrict__ sorted, int E, int NB, int nblk) {
    __shared__ int vals[PMAX];
    __shared__ int work[PMAX];
    __shared__ int ofs[NBMAX];
    const int t = threadIdx.x, blk = blockIdx.x;

    int tot0 = 0, pre0 = 0, tot1 = 0, pre1 = 0;
    const int i0 = t, i1 = t + 256;
    for (int b2 = 0; b2 < nblk; ++b2) {
        const int* row = histG + (size_t)b2 * NB;
        if (i0 < NB) {
            int v = row[i0];
            tot0 += v;
            if (b2 < blk) pre0 += v;
        }
        if (i1 < NB) {
            int v = row[i1];
            tot1 += v;
            if (b2 < blk) pre1 += v;
        }
    }
    vals[t] = (i0 < NB) ? tot0 : 0;
    vals[t + 256] = (i1 < NB) ? tot1 : 0;
    __syncthreads();
    for (int o = 1; o < PMAX; o <<= 1) {  // inclusive scan, ping-pong
        for (int i = t; i < PMAX; i += 256) work[i] = vals[i] + ((i >= o) ? vals[i - o] : 0);
        __syncthreads();
        for (int i = t; i < PMAX; i += 256) vals[i] = work[i];
        __syncthreads();
    }
    if (i0 < NB) ofs[i0] = ((i0 == 0) ? 0 : vals[i0 - 1]) + pre0;
    if (i1 < NB) ofs[i1] = ((i1 == 0) ? 0 : vals[i1 - 1]) + pre1;
    if (blk == 0) {
        for (int i = t; i < NB; i += 256) bucketBase[i] = (i == 0) ? 0 : vals[i - 1];
        if (t == 0) bucketBase[NB] = E;
    }
    __syncthreads();

    int lo = blk * CHUNK, hi = min(lo + CHUNK, E);
    for (int i = lo + t; i < hi; i += 256) {
        int d = dst[i];
        int pos = atomicAdd(&ofs[d >> BSH], 1);
        sorted[pos] = (src[i] << BSH) | (d & (BN - 1));
    }
}

// ============ K3: per-bucket node-sort -> rowstart, dinv, csr_src ============
__global__ __launch_bounds__(256) void bucket_build(const int* __restrict__ bucketBase,
                                                    const int* __restrict__ sorted,
                                                    int* __restrict__ rowstart,
                                                    float* __restrict__ dinv,
                                                    int* __restrict__ csr_src, int N, int E,
                                                    int NB) {
    __shared__ int ent[LCAP];
    __shared__ int hist[BN];
    __shared__ int lofs[BN];
    const int b = blockIdx.x, t = threadIdx.x;

    const int base = bucketBase[b];
    const int endb = bucketBase[b + 1];
    int total = min(endb - base, LCAP);
    if (b == 0 && t == 0) rowstart[N] = E;

    for (int i = t; i < total; i += 256) ent[i] = sorted[base + i];
    if (t < BN) hist[t] = 0;
    __syncthreads();
    for (int i = t; i < total; i += 256) atomicAdd(&hist[ent[i] & (BN - 1)], 1);
    __syncthreads();
    if (t < BN) lofs[t] = hist[t];
    __syncthreads();
    for (int o = 1; o < BN; o <<= 1) {
        int v = (t < BN && t >= o) ? lofs[t - o] : 0;
        __syncthreads();
        if (t < BN) lofs[t] += v;
        __syncthreads();
    }
    if (t < BN) {
        int ex = lofs[t] - hist[t];
        int node = (b << BSH) + t;
        if (node < N) {
            rowstart[node] = base + ex;
            dinv[node] = rsqrtf((float)hist[t] + 1.0f);  // +1 self-loop
        }
        lofs[t] = ex;
    }
    __syncthreads();
    for (int i = t; i < total; i += 256) {
        int e = ent[i];
        int pos = atomicAdd(&lofs[e & (BN - 1)], 1);
        csr_src[base + pos] = e >> BSH;
    }
}

// ============ K4: gather1 + bias + relu (2 nodes/wave, 32 lanes x f16x4), f16 ============
__global__ __launch_bounds__(256) void gather1(const int* __restrict__ rowstart,
                                               const int* __restrict__ csr_src,
                                               const float* __restrict__ dinv,
                                               const f16* __restrict__ h,
                                               const float* __restrict__ b1,
                                               f16* __restrict__ r1, int N) {
    int wave = (blockIdx.x * 256 + threadIdx.x) >> 6;
    int lane = threadIdx.x & 63;
    int sub = lane >> 5, l32 = lane & 31;
    int node = wave * 2 + sub;
    if (node >= N) return;
    int beg = rowstart[node], end = rowstart[node + 1];
    float dn = dinv[node];
    const f16x4* hv = (const f16x4*)h;  // 32 f16x4 per 128-feat row

    f16x4 sv = hv[(size_t)node * 32 + l32];
    float a0 = dn * (float)sv[0], a1 = dn * (float)sv[1];
    float a2 = dn * (float)sv[2], a3 = dn * (float)sv[3];
    int i = beg;
    for (; i + 2 <= end; i += 2) {
        int s0 = csr_src[i], s1 = csr_src[i + 1];
        float w0 = dinv[s0], w1 = dinv[s1];
        f16x4 v0 = hv[(size_t)s0 * 32 + l32];
        f16x4 v1 = hv[(size_t)s1 * 32 + l32];
        a0 = fmaf(w0, (float)v0[0], a0); a1 = fmaf(w0, (float)v0[1], a1);
        a2 = fmaf(w0, (float)v0[2], a2); a3 = fmaf(w0, (float)v0[3], a3);
        a0 = fmaf(w1, (float)v1[0], a0); a1 = fmaf(w1, (float)v1[1], a1);
        a2 = fmaf(w1, (float)v1[2], a2); a3 = fmaf(w1, (float)v1[3], a3);
    }
    if (i < end) {
        int s = csr_src[i];
        float w = dinv[s];
        f16x4 v = hv[(size_t)s * 32 + l32];
        a0 = fmaf(w, (float)v[0], a0); a1 = fmaf(w, (float)v[1], a1);
        a2 = fmaf(w, (float)v[2], a2); a3 = fmaf(w, (float)v[3], a3);
    }
    float4 bb = ((const float4*)b1)[l32];
    f16x4 o;
    o[0] = (f16)fmaxf(fmaf(dn, a0, bb.x), 0.f);
    o[1] = (f16)fmaxf(fmaf(dn, a1, bb.y), 0.f);
    o[2] = (f16)fmaxf(fmaf(dn, a2, bb.z), 0.f);
    o[3] = (f16)fmaxf(fmaf(dn, a3, bb.w), 0.f);
    ((f16x4*)r1)[(size_t)node * 32 + l32] = o;
}

// ============ K5: MFMA GEMM2: h2[N x 64] = r1 @ W2 ============
__global__ __launch_bounds__(256) void gemm2(const f16* __restrict__ r1,
                                             const float* __restrict__ W2, f16* __restrict__ h2,
                                             int N) {
    __shared__ f16 aT[64 * 136];
    __shared__ f16 bT[64 * 136];  // W2^T [n][k]
    const int t = threadIdx.x;
    const int row0 = blockIdx.x * 64;
    {
        int r = t >> 2, s = (t & 3) * 32;
        bool ok = (row0 + r) < N;
        const f16* rp = r1 + (size_t)(row0 + r) * 128 + s;
        f16* dp = &aT[r * 136 + s];
#pragma unroll
        for (int c = 0; c < 4; ++c) {
            f16x8 hv;
            if (ok) hv = *(const f16x8*)(rp + c * 8);
            else {
#pragma unroll
                for (int j = 0; j < 8; ++j) hv[j] = (f16)0.f;
            }
            *(f16x8*)(dp + c * 8) = hv;
        }
    }
    for (int idx = t; idx < 128 * 64; idx += 256) {  // stage W2^T
        int k = idx >> 6, n = idx & 63;
        bT[n * 136 + k] = (f16)W2[idx];
    }
    __syncthreads();

    const int w = t >> 6, lane = t & 63, m15 = lane & 15, quad = lane >> 4;
    f32x4 acc[4];
#pragma unroll
    for (int c = 0; c < 4; ++c) acc[c] = (f32x4){0.f, 0.f, 0.f, 0.f};
    const f16* ar = &aT[(w * 16 + m15) * 136 + quad * 8];
#pragma unroll
    for (int k0 = 0; k0 < 128; k0 += 32) {
        f16x8 a = *(const f16x8*)(ar + k0);
#pragma unroll
        for (int c = 0; c < 4; ++c) {
            f16x8 b = *(const f16x8*)(&bT[(c * 16 + m15) * 136 + k0 + quad * 8]);
            acc[c] = __builtin_amdgcn_mfma_f32_16x16x32_f16(a, b, acc[c], 0, 0, 0);
        }
    }
#pragma unroll
    for (int c = 0; c < 4; ++c)
#pragma unroll
        for (int r = 0; r < 4; ++r) {
            int row = row0 + w * 16 + quad * 4 + r;
            if (row < N) h2[(size_t)row * 64 + c * 16 + m15] = (f16)acc[c][r];
        }
}

// ============ K6: gather2 + bias -> fp32 out (4 nodes/wave, 16 lanes x f16x4) ============
__global__ __launch_bounds__(256) void gather2(const int* __restrict__ rowstart,
                                               const int* __restrict__ csr_src,
                                               const float* __restrict__ dinv,
                                               const f16* __restrict__ h2,
                                               const float* __restrict__ b2,
                                               float* __restrict__ out, int N) {
    int wave = (blockIdx.x * 256 + threadIdx.x) >> 6;
    int lane = threadIdx.x & 63;
    int sub = lane >> 4, l16 = lane & 15;
    int node = wave * 4 + sub;
    if (node >= N) return;
    int beg = rowstart[node], end = rowstart[node + 1];
    float dn = dinv[node];
    const f16x4* h2v = (const f16x4*)h2;  // 16 f16x4 per 64-feat row

    f16x4 sv = h2v[(size_t)node * 16 + l16];
    float a0 = dn * (float)sv[0], a1 = dn * (float)sv[1];
    float a2 = dn * (float)sv[2], a3 = dn * (float)sv[3];
    int i = beg;
    for (; i + 2 <= end; i += 2) {
        int s0 = csr_src[i], s1 = csr_src[i + 1];
        float w0 = dinv[s0], w1 = dinv[s1];
        f16x4 v0 = h2v[(size_t)s0 * 16 + l16];
        f16x4 v1 = h2v[(size_t)s1 * 16 + l16];
        a0 = fmaf(w0, (float)v0[0], a0); a1 = fmaf(w0, (float)v0[1], a1);
        a2 = fmaf(w0, (float)v0[2], a2); a3 = fmaf(w0, (float)v0[3], a3);
        a0 = fmaf(w1, (float)v1[0], a0); a1 = fmaf(w1, (float)v1[1], a1);
        a2 = fmaf(w1, (float)v1[2], a2); a3 = fmaf(w1, (float)v1[3], a3);
    }
    if (i < end) {
        int s = csr_src[i];
        float w = dinv[s];
        f16x4 v = h2v[(size_t)s * 16 + l16];
        a0 = fmaf(w, (float)v[0], a0); a1 = fmaf(w, (float)v[1], a1);
        a2 = fmaf(w, (float)v[2], a2); a3 = fmaf(w, (float)v[3], a3);
    }
    float4 bb = ((const float4*)b2)[l16];
    float4 o;
    o.x = fmaf(dn, a0, bb.x);
    o.y = fmaf(dn, a1, bb.y);
    o.z = fmaf(dn, a2, bb.z);
    o.w = fmaf(dn, a3, bb.w);
    ((float4*)out)[(size_t)node * 16 + l16] = o;
}

extern "C" void kernel_launch(void* const* d_in, const int* in_sizes, int n_in,
                              void* d_out, int out_size, void* d_ws, size_t ws_size,
                              hipStream_t stream) {
    const float* x  = (const float*)d_in[0];
    const int*   ei = (const int*)d_in[1];
    const float* W1 = (const float*)d_in[2];
    const float* b1 = (const float*)d_in[3];
    const float* W2 = (const float*)d_in[4];
    const float* b2 = (const float*)d_in[5];

    const int N = in_sizes[0] / 128;  // 50000
    const int E = in_sizes[1] / 2;    // 800000
    const int* src = ei;
    const int* dst = ei + E;
    const int NB   = (N + BN - 1) >> BSH;      // 391
    const int nblk = (E + CHUNK - 1) / CHUNK;  // 196
    const int L    = NB * nblk;                // 76,636

    char* p = (char*)d_ws;
    auto bump = [&](size_t bytes) {
        char* r = p;
        p += (bytes + 255) & ~(size_t)255;
        return r;
    };
    int*   histG      = (int*)bump((size_t)L * 4);
    int*   bucketBase = (int*)bump((size_t)(NB + 1) * 4);
    int*   sorted     = (int*)bump((size_t)E * 4);
    int*   rowstart   = (int*)bump((size_t)(N + 1) * 4);
    float* dinv       = (float*)bump((size_t)N * 4);
    int*   csr_src    = (int*)bump((size_t)E * 4);
    f16*   h          = (f16*)bump((size_t)N * 128 * 2);
    f16*   r1         = (f16*)bump((size_t)N * 128 * 2);
    f16*   h2         = (f16*)bump((size_t)N * 64 * 2);
    float* out        = (float*)d_out;

    // K1: bucket-hist (transposed histG) || MFMA gemm1 (x@W1 -> h f16)
    k1<<<nblk + (N + 63) / 64, 256, 0, stream>>>(x, W1, dst, h, histG, N, E, NB, nblk);
    // K2: place edges bucket-contiguously (self-computed scan; publishes bucketBase)
    place<<<nblk, 256, 0, stream>>>(src, dst, histG, bucketBase, sorted, E, NB, nblk);
    // K3: per-bucket node sort -> rowstart, dinv, csr_src
    bucket_build<<<NB, 256, 0, stream>>>(bucketBase, sorted, rowstart, dinv, csr_src, N, E, NB);
    // K4: gather1 + b1 + relu -> r1 (f16), 2 nodes/wave
    gather1<<<(N / 2 + 3) / 4, 256, 0, stream>>>(rowstart, csr_src, dinv, h, b1, r1, N);
    // K5: MFMA gemm2 (r1@W2 -> h2 f16)
    gemm2<<<(N + 63) / 64, 256, 0, stream>>>(r1, W2, h2, N);
    // K6: gather2 + b2 -> out (fp32), 4 nodes/wave
    gather2<<<(N / 4 + 3) / 4, 256, 0, stream>>>(rowstart, csr_src, dinv, h2, b2, out, N);
}